// Round 4
// baseline (469.598 us; speedup 1.0000x reference)
//
#include <hip/hip_runtime.h>

// LSTM cell: fp32 inputs, fp32 output (bf16-lenient compare).
// gates[B,3H] = x@Wx^T + h@Wh^T + b; new_c = sig(gf)*c + sig(gi)*tanh(gg).
// M=16384, N=1024 x 3 gates, K=2048 (x||h fused).
//
// v5: deep-pipeline GEMM (512 thr / 8 waves) + merged coalesced pack.
//  - pack_all: one dispatch; wave-task = one 2KB fragment chunk; lane l reads
//    4x16B from row (l&31) (full 128B-line use via L1), stores coalesced 1KB.
//  - lstm_gemm: BM=256 x BN=64x3g, 8 waves (4M x 2N); A in VGPRs with
//    2-phase lookahead (triple buffer a0/a1/a2); B via global_load_lds ring-4
//    (4 x 24KB = 96KB LDS, 1 block/CU); uniform s_waitcnt vmcnt(14) per phase
//    (waits only 2-3-phase-old loads); raw s_barrier; setprio MFMA cluster.
//  A ws: [m32t:512][cg:64][ks:2][lane:64][16B]  (64 MB)
//  W ws: [nt32:32][k64t:32][g:3][khalf:2][ks:2][lane:64][16B]  (12 MB)

#define HS 1024

typedef __bf16 bf16;
typedef bf16  bf16x4  __attribute__((ext_vector_type(4)));
typedef bf16  bf16x8  __attribute__((ext_vector_type(8)));
typedef float f32x4   __attribute__((ext_vector_type(4)));
typedef float f32x16  __attribute__((ext_vector_type(16)));

#define WAITVM(N) asm volatile("s_waitcnt vmcnt(" #N ")" ::: "memory")
#define WAITLGKM0 asm volatile("s_waitcnt lgkmcnt(0)" ::: "memory")
#define BARRIER   asm volatile("s_barrier" ::: "memory")

__device__ __forceinline__ void cp16(void* lds, const void* g) {
  __builtin_amdgcn_global_load_lds(
      (const __attribute__((address_space(1))) void*)g,
      (__attribute__((address_space(3))) void*)lds, 16, 0, 0);
}

__device__ __forceinline__ bf16x8 cvt8(const f32x4 v0, const f32x4 v1) {
  bf16x8 o;
  o[0] = (bf16)v0[0]; o[1] = (bf16)v0[1]; o[2] = (bf16)v0[2]; o[3] = (bf16)v0[3];
  o[4] = (bf16)v1[0]; o[5] = (bf16)v1[1]; o[6] = (bf16)v1[2]; o[7] = (bf16)v1[3];
  return o;
}

// ---------------------------------------------------------------------------
// pack_all: A-tasks (waves 0..32767) then W-tasks (waves 32768..38911).
// Wave-task = one 2KB fragment pair. lane l: row = base+(l&31),
// cols = cgbase + ks*16 + (l>>5)*8; store at +ks*1024 + l*16 (coalesced 1KB).
__global__ __launch_bounds__(256) void pack_all(
    const float* __restrict__ x, const float* __restrict__ h,
    const float* __restrict__ w_ii, const float* __restrict__ w_hi,
    const float* __restrict__ w_if, const float* __restrict__ w_hf,
    const float* __restrict__ w_ig, const float* __restrict__ w_hg,
    bf16* __restrict__ Aws, bf16* __restrict__ Wws) {
  const int wid  = blockIdx.x * 4 + (threadIdx.x >> 6);
  const int lane = threadIdx.x & 63;
  const float* src;
  char* dst;
  if (wid < 32768) {                       // ---- A = [x | h]
    const int m32t = wid >> 6;
    const int cg   = wid & 63;             // k32-group: 0..31 x, 32..63 h
    const int r    = m32t * 32 + (lane & 31);
    const float* base = (cg < 32) ? (x + (size_t)r * HS + cg * 32)
                                  : (h + (size_t)r * HS + (cg - 32) * 32);
    src = base + (lane >> 5) * 8;
    dst = (char*)Aws + (size_t)m32t * 131072u + (unsigned)cg * 2048u + lane * 16;
  } else {                                 // ---- W (3 gates, x||h fused)
    const int wid2 = wid - 32768;
    const int g    = wid2 >> 11;           // 2048 wave-tasks per gate
    const int rem  = wid2 & 2047;
    const int nt32 = rem >> 6;
    const int cg   = rem & 63;
    const int n    = nt32 * 32 + (lane & 31);
    const float* wx = (g == 0) ? w_ii : (g == 1) ? w_if : w_ig;
    const float* wh = (g == 0) ? w_hi : (g == 1) ? w_hf : w_hg;
    const float* base = (cg < 32) ? (wx + (size_t)n * HS + cg * 32)
                                  : (wh + (size_t)n * HS + (cg - 32) * 32);
    src = base + (lane >> 5) * 8;
    const int k64t = cg >> 1, khalf = cg & 1;
    dst = (char*)Wws + (size_t)nt32 * 393216u + (unsigned)k64t * 12288u
        + (unsigned)g * 4096u + (unsigned)khalf * 2048u + lane * 16;
  }
#pragma unroll
  for (int ks = 0; ks < 2; ++ks) {
    const f32x4 v0 = *(const f32x4*)(src + ks * 16);
    const f32x4 v1 = *(const f32x4*)(src + ks * 16 + 4);
    *(bf16x8*)(dst + ks * 1024) = cvt8(v0, v1);
  }
}

// ---------------------------------------------------------------------------
// GEMM: block = 256M x 64N x 3 gates, 512 thr = 8 waves (4M x 2N);
// wave = 64M x 32N x 3g = 24 MFMA per K64 phase. 32 phases.
__global__ __launch_bounds__(512, 2) void lstm_gemm(
    const bf16* __restrict__ Aws, const bf16* __restrict__ Wws,
    const float* __restrict__ c,
    const float* __restrict__ b_ii, const float* __restrict__ b_hi,
    const float* __restrict__ b_if, const float* __restrict__ b_hf,
    const float* __restrict__ b_ig, const float* __restrict__ b_hg,
    float* __restrict__ out)
{
  __shared__ __align__(16) char smem[4 * 24576];   // ring-4 x 24KB = 96 KB

  const int tid  = threadIdx.x;
  const int lane = tid & 63;
  const int wave = tid >> 6;
  const int wm4  = wave & 3;     // M sub-tile (4 x 64 rows)
  const int wn2  = wave >> 2;    // N sub-tile (2 x 32 cols)
  const int lb   = lane * 16;

  // XCD-bijective swizzle: 1024 wgs = 8 XCD x 128 contiguous.
  const int bid = blockIdx.x;
  const int wg  = (bid & 7) * 128 + (bid >> 3);
  const int nt  = wg & 15;       // nt-minor: co-resident blocks share A panels
  const int mt  = wg >> 4;

  const char* Apan0 = (const char*)Aws + (size_t)(mt * 8 + wm4 * 2) * 131072u + lb;
  const char* Apan1 = Apan0 + 131072;
  // this wave stages (and reads) its own 12KB B half (wn2); 3KB slice per wave
  const char* Wsrc  = (const char*)Wws + (size_t)(nt * 2 + wn2) * 393216u
                    + (wave & 3) * 3072 + lb;

  f32x16 acc[3][2] = {};

  auto stageB = [&](int t) {
    char* d = smem + (t & 3) * 24576 + wn2 * 12288 + (wave & 3) * 3072;
    const char* s = Wsrc + (size_t)t * 12288u;
    cp16(d,        s);
    cp16(d + 1024, s + 1024);
    cp16(d + 2048, s + 2048);
  };

  auto loadA = [&](int t, bf16x8 (&d)[2][4]) {
#pragma unroll
    for (int j = 0; j < 4; ++j) {
      d[0][j] = *(const bf16x8*)(Apan0 + t * 4096 + j * 1024);
      d[1][j] = *(const bf16x8*)(Apan1 + t * 4096 + j * 1024);
    }
  };

  auto compute = [&](int t, const bf16x8 (&a)[2][4]) {
    const char* bufB = smem + (t & 3) * 24576 + wn2 * 12288 + lb;
    __builtin_amdgcn_s_setprio(1);
#pragma unroll
    for (int ks = 0; ks < 4; ++ks) {
      const bf16x8 b0 = *(const bf16x8*)(bufB + (0 * 4 + ks) * 1024);
      const bf16x8 b1 = *(const bf16x8*)(bufB + (1 * 4 + ks) * 1024);
      const bf16x8 b2 = *(const bf16x8*)(bufB + (2 * 4 + ks) * 1024);
      acc[0][0] = __builtin_amdgcn_mfma_f32_32x32x16_bf16(a[0][ks], b0, acc[0][0], 0, 0, 0);
      acc[0][1] = __builtin_amdgcn_mfma_f32_32x32x16_bf16(a[1][ks], b0, acc[0][1], 0, 0, 0);
      acc[1][0] = __builtin_amdgcn_mfma_f32_32x32x16_bf16(a[0][ks], b1, acc[1][0], 0, 0, 0);
      acc[1][1] = __builtin_amdgcn_mfma_f32_32x32x16_bf16(a[1][ks], b1, acc[1][1], 0, 0, 0);
      acc[2][0] = __builtin_amdgcn_mfma_f32_32x32x16_bf16(a[0][ks], b2, acc[2][0], 0, 0, 0);
      acc[2][1] = __builtin_amdgcn_mfma_f32_32x32x16_bf16(a[1][ks], b2, acc[2][1], 0, 0, 0);
    }
    __builtin_amdgcn_s_setprio(0);
  };

  bf16x8 a0[2][4], a1[2][4], a2[2][4];

  // Prologue issue order [B0, A0, A1, B1, B2] => every phase's WAITVM(14)
  // completes exactly {B(t), A(t)} (the 11 oldest), keeps 14 in flight:
  // {A(t+1), B(t+1), B(t+2)} / steady {B(t+1), A(t+1), B(t+2)}.
  stageB(0);
  loadA(0, a0);
  loadA(1, a1);
  stageB(1);
  stageB(2);

#define PHASE14(T_, CUR_, PRV_)                \
  WAITVM(14);                                  \
  WAITLGKM0;                                   \
  BARRIER;                                     \
  loadA((T_) + 2, PRV_);                       \
  if ((T_) + 3 < 32) stageB((T_) + 3);         \
  compute((T_), CUR_);

  for (int t = 0; t < 30; t += 3) {
    PHASE14(t,     a0, a2)
    PHASE14(t + 1, a1, a0)
    PHASE14(t + 2, a2, a1)
  }
#undef PHASE14

  // t = 30: outstanding {B30,A30,B31,A31}=22 -> finish B30+A30, keep 11.
  WAITVM(11); WAITLGKM0; BARRIER;
  compute(30, a0);
  // t = 31: drain.
  WAITVM(0); WAITLGKM0; BARRIER;
  compute(31, a1);

  // Epilogue. C/D 32x32 layout: col n = lane&31, row = (r&3)+8*(r>>2)+4*(lane>>5).
  const int n  = nt * 64 + wn2 * 32 + (lane & 31);
  const int rb = (lane >> 5) * 4;
  const float bi  = b_ii[n] + b_hi[n];
  const float bf_ = b_if[n] + b_hf[n];
  const float bg  = b_ig[n] + b_hg[n];
#pragma unroll
  for (int i = 0; i < 2; ++i) {
#pragma unroll
    for (int r = 0; r < 16; ++r) {
      const int m = mt * 256 + wm4 * 64 + i * 32 + (r & 3) + 8 * (r >> 2) + rb;
      const size_t idx = (size_t)m * HS + n;
      const float gi = acc[0][i][r] + bi;
      const float gf = acc[1][i][r] + bf_;
      const float gg = acc[2][i][r] + bg;
      const float it = 1.f / (1.f + __expf(-gi));
      const float ft = 1.f / (1.f + __expf(-gf));
      const float e2 = __expf(-2.f * gg);
      const float gt = (1.f - e2) / (1.f + e2);  // tanh
      out[idx] = ft * c[idx] + it * gt;
    }
  }
}

// ===========================================================================
// Legacy fallback — used only if workspace too small.
#define K_TOTAL 2048
#define BK      32
#define NITER   (K_TOTAL / BK)

__device__ __forceinline__ void ldpanel(const float* __restrict__ src, int tid,
                                        f32x4* __restrict__ v) {
#pragma unroll
  for (int b = 0; b < 2; ++b) {
    const int cc  = tid + b * 256;
    const int row = cc >> 3;
    const int col = (cc & 7) * 4;
    v[b] = *(const f32x4*)(src + (size_t)row * HS + col);
  }
}

__device__ __forceinline__ void stpanel(bf16* __restrict__ dst, int tid,
                                        const f32x4* __restrict__ v) {
#pragma unroll
  for (int b = 0; b < 2; ++b) {
    const int cc  = tid + b * 256;
    const int row = cc >> 3;
    const int col = (cc & 7) * 4;
    bf16x4 o;
    o[0] = (bf16)v[b][0]; o[1] = (bf16)v[b][1];
    o[2] = (bf16)v[b][2]; o[3] = (bf16)v[b][3];
    *(bf16x4*)(dst + row * 32 + col) = o;
  }
}

__device__ __forceinline__ void get_srcs(
    int k, int m0, int n0,
    const float* __restrict__ x, const float* __restrict__ h,
    const float* __restrict__ w_ii, const float* __restrict__ w_hi,
    const float* __restrict__ w_if, const float* __restrict__ w_hf,
    const float* __restrict__ w_ig, const float* __restrict__ w_hg,
    const float* s[5]) {
  const int kk = k * BK;
  const float* Ag; const float* w0; const float* w1; const float* w2; int kl;
  if (kk < 1024) { Ag = x; w0 = w_ii; w1 = w_if; w2 = w_ig; kl = kk; }
  else           { Ag = h; w0 = w_hi; w1 = w_hf; w2 = w_hg; kl = kk - 1024; }
  s[0] = Ag + (size_t)m0 * HS + kl;
  s[1] = Ag + (size_t)(m0 + 64) * HS + kl;
  s[2] = w0 + (size_t)n0 * HS + kl;
  s[3] = w1 + (size_t)n0 * HS + kl;
  s[4] = w2 + (size_t)n0 * HS + kl;
}

__global__ __launch_bounds__(256, 2) void lstm_fused(
    const float* __restrict__ x, const float* __restrict__ h,
    const float* __restrict__ c,
    const float* __restrict__ w_ii, const float* __restrict__ w_hi,
    const float* __restrict__ w_if, const float* __restrict__ w_hf,
    const float* __restrict__ w_ig, const float* __restrict__ w_hg,
    const float* __restrict__ b_ii, const float* __restrict__ b_hi,
    const float* __restrict__ b_if, const float* __restrict__ b_hf,
    const float* __restrict__ b_ig, const float* __restrict__ b_hg,
    float* __restrict__ out)
{
  __shared__ bf16 smem[2 * 10240];

  const int tid  = threadIdx.x;
  const int lane = tid & 63;
  const int wave = tid >> 6;

  const int bid = blockIdx.x;
  const int nt  = bid & 15;
  const int mt  = bid >> 4;
  const int m0  = mt * 128;
  const int n0  = nt * 64;
  const int wm  = (wave & 1) * 64;
  const int wn  = (wave >> 1) * 32;

  f32x16 acc[3][2] = {};

  {
    const float* s[5];
    get_srcs(0, m0, n0, x, h, w_ii, w_hi, w_if, w_hf, w_ig, w_hg, s);
    f32x4 pf[5][2];
#pragma unroll
    for (int p = 0; p < 5; ++p) ldpanel(s[p], tid, pf[p]);
    bf16* A0 = smem;
#pragma unroll
    for (int p = 0; p < 5; ++p) stpanel(A0 + p * 2048, tid, pf[p]);
    __syncthreads();
  }

  const int fr  = lane & 31;
  const int fk8 = (lane >> 5) * 8;

  for (int k = 0; k < NITER; ++k) {
    bf16* As = smem + (k & 1) * 10240;
    bf16* Bs = As + 4096;

    f32x4 nf[5][2];
    if (k < NITER - 1) {
      const float* s[5];
      get_srcs(k + 1, m0, n0, x, h, w_ii, w_hi, w_if, w_hf, w_ig, w_hg, s);
#pragma unroll
      for (int p = 0; p < 5; ++p) ldpanel(s[p], tid, nf[p]);
    }

#pragma unroll
    for (int ks = 0; ks < 2; ++ks) {
      const int co = ks * 16 + fk8;
      bf16x8 a0 = *(const bf16x8*)(As + (wm + fr) * 32 + co);
      bf16x8 a1 = *(const bf16x8*)(As + (wm + 32 + fr) * 32 + co);
#pragma unroll
      for (int g = 0; g < 3; ++g) {
        bf16x8 b = *(const bf16x8*)(Bs + g * 2048 + (wn + fr) * 32 + co);
        acc[g][0] = __builtin_amdgcn_mfma_f32_32x32x16_bf16(a0, b, acc[g][0], 0, 0, 0);
        acc[g][1] = __builtin_amdgcn_mfma_f32_32x32x16_bf16(a1, b, acc[g][1], 0, 0, 0);
      }
    }

    if (k < NITER - 1) {
      bf16* An = smem + ((k + 1) & 1) * 10240;
#pragma unroll
      for (int p = 0; p < 5; ++p) stpanel(An + p * 2048, tid, nf[p]);
    }
    __syncthreads();
  }

  const int n   = n0 + wn + (lane & 31);
  const int rb  = (lane >> 5) * 4;
  const float bi  = b_ii[n] + b_hi[n];
  const float bf_ = b_if[n] + b_hf[n];
  const float bg  = b_ig[n] + b_hg[n];
#pragma unroll
  for (int i = 0; i < 2; ++i) {
#pragma unroll
    for (int r = 0; r < 16; ++r) {
      const int m = m0 + wm + i * 32 + (r & 3) + 8 * (r >> 2) + rb;
      const size_t idx = (size_t)m * HS + n;
      const float gi = acc[0][i][r] + bi;
      const float gf = acc[1][i][r] + bf_;
      const float gg = acc[2][i][r] + bg;
      const float it = 1.f / (1.f + __expf(-gi));
      const float ft = 1.f / (1.f + __expf(-gf));
      const float e2 = __expf(-2.f * gg);
      const float gt = (1.f - e2) / (1.f + e2);
      out[idx] = ft * c[idx] + it * gt;
    }
  }
}

// ===========================================================================
extern "C" void kernel_launch(void* const* d_in, const int* in_sizes, int n_in,
                              void* d_out, int out_size, void* d_ws, size_t ws_size,
                              hipStream_t stream) {
  const float* x  = (const float*)d_in[0];
  const float* h  = (const float*)d_in[1];
  const float* c  = (const float*)d_in[2];
  const float* w_ii = (const float*)d_in[3];
  const float* b_ii = (const float*)d_in[4];
  const float* w_hi = (const float*)d_in[5];
  const float* b_hi = (const float*)d_in[6];
  const float* w_if = (const float*)d_in[7];
  const float* b_if = (const float*)d_in[8];
  const float* w_hf = (const float*)d_in[9];
  const float* b_hf = (const float*)d_in[10];
  const float* w_ig = (const float*)d_in[11];
  const float* b_ig = (const float*)d_in[12];
  const float* w_hg = (const float*)d_in[13];
  const float* b_hg = (const float*)d_in[14];
  float* out = (float*)d_out;

  const size_t needA = (size_t)512 * 131072u;   // 64 MB
  const size_t needW = (size_t)32 * 393216u;    // 12 MB

  if (ws_size >= needA + needW) {
    bf16* Aws = (bf16*)d_ws;
    bf16* Wws = (bf16*)((char*)d_ws + needA);
    hipLaunchKernelGGL(pack_all, dim3(9728), dim3(256), 0, stream,
                       x, h, w_ii, w_hi, w_if, w_hf, w_ig, w_hg, Aws, Wws);
    hipLaunchKernelGGL(lstm_gemm, dim3(1024), dim3(512), 0, stream,
                       Aws, Wws, c, b_ii, b_hi, b_if, b_hf, b_ig, b_hg, out);
  } else {
    hipLaunchKernelGGL(lstm_fused, dim3(2048), dim3(256), 0, stream,
                       x, h, c, w_ii, w_hi, w_if, w_hf, w_ig, w_hg,
                       b_ii, b_hi, b_if, b_hf, b_ig, b_hg, out);
  }
}